// Round 12
// baseline (67.865 us; speedup 1.0000x reference)
//
#include <hip/hip_runtime.h>
#include <math.h>

namespace {
constexpr int B_ = 32, C_ = 256, H_ = 32, W_ = 128, A_ = 64;
constexpr int AA = A_ * A_;       // 4096 positions per batch
constexpr int HW = H_ * W_;       // 4096 floats per (b,c) image = 16 KB
constexpr int NPOS = B_ * AA;     // 131072
constexpr int CPB = 16;           // channels per block
constexpr int TPB = 512;          // threads per block (8 waves)
constexpr int PHALF = AA / 2;     // positions per block (z-split)
constexpr float MPP = 1.6f;       // 0.2 * 512 / 64
constexpr float PI_F = 3.14159265358979323846f;
typedef float vf4 __attribute__((ext_vector_type(4)));   // native vec for NT store
}

struct Pmat {
    float p00, p01, p02, p03;
    float p10, p11, p12, p13;
    float p20, p21, p22, p23;
};

__device__ __forceinline__ Pmat make_P(int b,
                                       const float* __restrict__ shift_u,
                                       const float* __restrict__ shift_v,
                                       const float* __restrict__ heading,
                                       const float* __restrict__ camk) {
    float su = 20.f * shift_u[b];
    float sv = 20.f * shift_v[b];
    float h  = heading[b] * (10.f / 180.f) * PI_F;
    float ch = cosf(h);
    float sh = -sinf(h);   // sin(-h)

    const float* K = camk + b * 9;
    float k00 = K[0] * 0.125f, k01 = K[1] * 0.125f, k02 = K[2] * 0.125f;
    float k10 = K[3] * 0.125f, k11 = K[4] * 0.125f, k12 = K[5] * 0.125f;
    float k20 = K[6],          k21 = K[7],          k22 = K[8];

    Pmat P;
    P.p00 = k00 * ch + k02 * sh;  P.p01 = k01;
    P.p02 = -k00 * sh + k02 * ch; P.p03 = k00 * sv + k01 * 1.65f - k02 * su;
    P.p10 = k10 * ch + k12 * sh;  P.p11 = k11;
    P.p12 = -k10 * sh + k12 * ch; P.p13 = k10 * sv + k11 * 1.65f - k12 * su;
    P.p20 = k20 * ch + k22 * sh;  P.p21 = k21;
    P.p22 = -k20 * sh + k22 * ch; P.p23 = k20 * sv + k21 * 1.65f - k22 * su;
    return P;
}

__device__ __forceinline__ float4 uv_at(const Pmat& P, int pos, float Y) {
    int i = pos >> 6, j = pos & 63;
    float X = MPP * (float)(i - 32);
    float Z = MPP * (float)(j - 32);

    float u1 = P.p00 * X + P.p02 * Z + P.p03;
    float v1 = P.p10 * X + P.p12 * Z + P.p13;
    float w1 = P.p20 * X + P.p22 * Z + P.p23;

    float d0 = fmaxf(w1, 1e-6f);
    float u0 = u1 / d0, v0 = v1 / d0;

    float u1h = u1 + P.p01 * Y;
    float v1h = v1 + P.p11 * Y;
    float w1h = w1 + P.p21 * Y;
    float dh = fmaxf(w1h, 1e-6f);
    float uh = u1h / dh, vh = v1h / dh;

    return make_float4(u0, v0, uh, vh);
}

// Kernel 1: per (b,pos) compute both UV pairs -> workspace [NPOS] float4
__global__ __launch_bounds__(256) void uv_kernel(
        const float* __restrict__ ph,
        const float* __restrict__ shift_u,
        const float* __restrict__ shift_v,
        const float* __restrict__ heading,
        const float* __restrict__ camk,
        float4* __restrict__ uvout) {
    int gid = blockIdx.x * 256 + threadIdx.x;
    if (gid >= NPOS) return;
    int b = gid >> 12;
    int pos = gid & (AA - 1);
    Pmat P = make_P(b, shift_u, shift_v, heading, camk);
    uvout[gid] = uv_at(P, pos, -ph[gid]);
}

// Weights premultiplied by valid; LDS dword index, unclamped +1/+128/+129 taps.
// Edge overflow taps carry weight exactly 0; they read the other buffer /
// zero tail, which is guaranteed finite (never NaN/inf from uninit).
__device__ __forceinline__ void mk(float ix, float iy, float4& w, int& ad) {
    bool valid = (ix >= 0.f) && (ix <= (float)(W_ - 1)) &&
                 (iy >= 0.f) && (iy <= (float)(H_ - 1));
    float x0f = floorf(ix), y0f = floorf(iy);
    float fx = ix - x0f, fy = iy - y0f;
    float xa = fminf(fmaxf(x0f, 0.f), 127.f);
    float ya = fminf(fmaxf(y0f, 0.f), 31.f);
    int a = (int)fmaf(ya, 128.f, xa);
    float gx = 1.f - fx, gy = 1.f - fy;
    w = valid ? make_float4(gx * gy, fx * gy, gx * fy, fx * fy)
              : make_float4(0.f, 0.f, 0.f, 0.f);
    ad = valid ? a : 0;
}

__device__ __forceinline__ float tap4(const float* __restrict__ im, int ad, float4 w) {
    const float* t = im + ad;
    return fmaf(w.x, t[0], fmaf(w.y, t[1], fmaf(w.z, t[128], w.w * t[129])));
}

// Kernel 2: one block per (b, 16-channel group, position-half). 512 threads
// x 4 positions = 2048 positions/block; grid 1024 blocks -> 4 blocks/CU x
// 8 waves = 32 waves in FOUR independent barrier domains, so one block's
// staging overlaps the others' compute. Inner pipeline per channel is the
// proven r8/r11 one: {ds_write staged -> reg-prefetch next -> lgkmcnt-only
// barrier (prefetch stays in flight) -> compute + NT store}.
// z-sibling blocks stage the same images; dup reads hit L2/L3 (z-siblings
// are 512 apart in linear block id -> same XCD round-robin slot).
template <bool PRECOMP>
__global__ __launch_bounds__(TPB) void proj_kernel(
        const float* __restrict__ grd,
        const float4* __restrict__ uv,
        const float* __restrict__ sat,
        float* __restrict__ out,
        const float* __restrict__ ph,    // inline-fallback path
        const float* __restrict__ shift_u,
        const float* __restrict__ shift_v,
        const float* __restrict__ heading,
        const float* __restrict__ camk) {
    __shared__ float img[2 * HW + 132];
    int cg = blockIdx.x, b = blockIdx.y, z = blockIdx.z;
    int c0 = cg * CPB;
    int tid = threadIdx.x;
    int p0 = z * PHALF + tid * 4;    // this block's position range
    int bbase = b << 12;

    const float* gbase = grd + ((size_t)b * C_ + c0) * HW;

    // prologue: issue load of channel 0 image (2 float4/thread: 512 thr x 32B)
    float4 sA = ((const float4*)gbase)[tid];
    float4 sB = ((const float4*)gbase)[TPB + tid];

    // zero-init buf1 head + permanent tail (overflow-tap safety on iter 0)
    if (tid < 33) {
        ((float4*)(img + HW))[tid] = make_float4(0.f, 0.f, 0.f, 0.f);
        ((float4*)(img + 2 * HW))[tid] = make_float4(0.f, 0.f, 0.f, 0.f);
    }

    // per-position sampling descriptors, computed once for all 16 channels
    float4 w[4][2];
    int ad[4][2];
    if (PRECOMP) {
        const float4* uvb = uv + bbase;
#pragma unroll
        for (int k = 0; k < 4; ++k) {
            float4 q = uvb[p0 + k];
            mk(q.x, q.y, w[k][0], ad[k][0]);
            mk(q.z, q.w, w[k][1], ad[k][1]);
        }
    } else {
        Pmat P = make_P(b, shift_u, shift_v, heading, camk);
        const float* phb = ph + bbase;
#pragma unroll
        for (int k = 0; k < 4; ++k) {
            float4 q = uv_at(P, p0 + k, -phb[p0 + k]);
            mk(q.x, q.y, w[k][0], ad[k][0]);
            mk(q.z, q.w, w[k][1], ad[k][1]);
        }
    }

    float* outbase = out + ((size_t)b * C_ + c0) * AA + p0;
    const float* satbase = sat + (size_t)c0 * AA + p0;

#pragma unroll
    for (int cp = 0; cp < CPB; ++cp) {
        int bufo = (cp & 1) * HW;
        // stage current channel (regs -> LDS, 2 float4/thread)
        *(float4*)(img + bufo + tid * 4) = sA;
        *(float4*)(img + bufo + (TPB + tid) * 4) = sB;
        // prefetch next channel (stays in flight across the barrier)
        float4 nA, nB;
        if (cp + 1 < CPB) {
            const float4* gn = (const float4*)(gbase + (size_t)(cp + 1) * HW);
            nA = gn[tid];
            nB = gn[TPB + tid];
        }
        float4 sv = *(const float4*)(satbase + (size_t)cp * AA);
        // barrier with LDS-only drain: do NOT wait vmcnt (prefetch in flight)
        asm volatile("s_waitcnt lgkmcnt(0)" ::: "memory");
        __builtin_amdgcn_s_barrier();

        const float* im = img + bufo;
        float r[4];
#pragma unroll
        for (int k = 0; k < 4; ++k) {
            float g0 = tap4(im, ad[k][0], w[k][0]);
            float gh = tap4(im, ad[k][1], w[k][1]);
            float s = (k == 0) ? sv.x : (k == 1) ? sv.y : (k == 2) ? sv.z : sv.w;
            r[k] = fmaf(s, gh - g0, g0);
        }
        vf4 rv = {r[0], r[1], r[2], r[3]};
        __builtin_nontemporal_store(rv, (vf4*)(outbase + (size_t)cp * AA));
        sA = nA; sB = nB;
        // Laggard-safety: a wave's reads of buffer X (iter cp) are drained by
        // its own lgkmcnt(0) before barrier cp+1; writers of X (iter cp+2)
        // write only after barrier cp+1 -> no read/write race.
    }
}

extern "C" void kernel_launch(void* const* d_in, const int* in_sizes, int n_in,
                              void* d_out, int out_size, void* d_ws, size_t ws_size,
                              hipStream_t stream) {
    (void)in_sizes; (void)n_in; (void)out_size;
    const float* grd  = (const float*)d_in[0];   // [B,C,H,W]
    const float* ph   = (const float*)d_in[1];   // [B,1,A,A]
    const float* s_u  = (const float*)d_in[2];   // [B,1]
    const float* s_v  = (const float*)d_in[3];   // [B,1]
    const float* hd   = (const float*)d_in[4];   // [B,1]
    const float* ck   = (const float*)d_in[5];   // [B,3,3]
    const float* sat  = (const float*)d_in[6];   // [1,C,A,A]
    float* out = (float*)d_out;

    const size_t uv_bytes = (size_t)NPOS * sizeof(float4);   // 2 MiB
    if (ws_size >= uv_bytes) {
        float4* uvws = (float4*)d_ws;
        uv_kernel<<<(NPOS + 255) / 256, 256, 0, stream>>>(ph, s_u, s_v, hd, ck, uvws);
        proj_kernel<true><<<dim3(C_ / CPB, B_, 2), TPB, 0, stream>>>(
            grd, uvws, sat, out, ph, s_u, s_v, hd, ck);
    } else {
        proj_kernel<false><<<dim3(C_ / CPB, B_, 2), TPB, 0, stream>>>(
            grd, nullptr, sat, out, ph, s_u, s_v, hd, ck);
    }
}

// Round 13
// 51.707 us; speedup vs baseline: 1.3125x; 1.3125x over previous
//
#include <hip/hip_runtime.h>
#include <math.h>

namespace {
constexpr int B_ = 32, C_ = 256, H_ = 32, W_ = 128, A_ = 64;
constexpr int AA = A_ * A_;       // 4096 positions per batch
constexpr int HW = H_ * W_;       // 4096 floats per (b,c) image = 16 KB
constexpr int NPOS = B_ * AA;     // 131072
constexpr int CPB = 16;           // channels per block -> 512 blocks
constexpr int TPB = 1024;         // threads per block (16 waves)
constexpr float MPP = 1.6f;       // 0.2 * 512 / 64
constexpr float PI_F = 3.14159265358979323846f;
typedef float vf4 __attribute__((ext_vector_type(4)));   // native vec for NT store
}

struct Pmat {
    float p00, p01, p02, p03;
    float p10, p11, p12, p13;
    float p20, p21, p22, p23;
};

__device__ __forceinline__ Pmat make_P(int b,
                                       const float* __restrict__ shift_u,
                                       const float* __restrict__ shift_v,
                                       const float* __restrict__ heading,
                                       const float* __restrict__ camk) {
    float su = 20.f * shift_u[b];
    float sv = 20.f * shift_v[b];
    float h  = heading[b] * (10.f / 180.f) * PI_F;
    float ch = cosf(h);
    float sh = -sinf(h);   // sin(-h)

    const float* K = camk + b * 9;
    float k00 = K[0] * 0.125f, k01 = K[1] * 0.125f, k02 = K[2] * 0.125f;
    float k10 = K[3] * 0.125f, k11 = K[4] * 0.125f, k12 = K[5] * 0.125f;
    float k20 = K[6],          k21 = K[7],          k22 = K[8];

    Pmat P;
    P.p00 = k00 * ch + k02 * sh;  P.p01 = k01;
    P.p02 = -k00 * sh + k02 * ch; P.p03 = k00 * sv + k01 * 1.65f - k02 * su;
    P.p10 = k10 * ch + k12 * sh;  P.p11 = k11;
    P.p12 = -k10 * sh + k12 * ch; P.p13 = k10 * sv + k11 * 1.65f - k12 * su;
    P.p20 = k20 * ch + k22 * sh;  P.p21 = k21;
    P.p22 = -k20 * sh + k22 * ch; P.p23 = k20 * sv + k21 * 1.65f - k22 * su;
    return P;
}

__device__ __forceinline__ float4 uv_at(const Pmat& P, int pos, float Y) {
    int i = pos >> 6, j = pos & 63;
    float X = MPP * (float)(i - 32);
    float Z = MPP * (float)(j - 32);

    float u1 = P.p00 * X + P.p02 * Z + P.p03;
    float v1 = P.p10 * X + P.p12 * Z + P.p13;
    float w1 = P.p20 * X + P.p22 * Z + P.p23;

    float d0 = fmaxf(w1, 1e-6f);
    float u0 = u1 / d0, v0 = v1 / d0;

    float u1h = u1 + P.p01 * Y;
    float v1h = v1 + P.p11 * Y;
    float w1h = w1 + P.p21 * Y;
    float dh = fmaxf(w1h, 1e-6f);
    float uh = u1h / dh, vh = v1h / dh;

    return make_float4(u0, v0, uh, vh);
}

// Kernel 1: per (b,pos) compute both UV pairs -> workspace [NPOS] float4
__global__ __launch_bounds__(256) void uv_kernel(
        const float* __restrict__ ph,
        const float* __restrict__ shift_u,
        const float* __restrict__ shift_v,
        const float* __restrict__ heading,
        const float* __restrict__ camk,
        float4* __restrict__ uvout) {
    int gid = blockIdx.x * 256 + threadIdx.x;
    if (gid >= NPOS) return;
    int b = gid >> 12;
    int pos = gid & (AA - 1);
    Pmat P = make_P(b, shift_u, shift_v, heading, camk);
    uvout[gid] = uv_at(P, pos, -ph[gid]);
}

// Weights premultiplied by valid; LDS dword index, unclamped +1/+128/+129 taps.
// Edge overflow taps carry weight exactly 0; they read the other buffer /
// zero tail, which is guaranteed finite (never NaN/inf from uninit).
__device__ __forceinline__ void mk(float ix, float iy, float4& w, int& ad) {
    bool valid = (ix >= 0.f) && (ix <= (float)(W_ - 1)) &&
                 (iy >= 0.f) && (iy <= (float)(H_ - 1));
    float x0f = floorf(ix), y0f = floorf(iy);
    float fx = ix - x0f, fy = iy - y0f;
    float xa = fminf(fmaxf(x0f, 0.f), 127.f);
    float ya = fminf(fmaxf(y0f, 0.f), 31.f);
    int a = (int)fmaf(ya, 128.f, xa);
    float gx = 1.f - fx, gy = 1.f - fy;
    w = valid ? make_float4(gx * gy, fx * gy, gx * fy, fx * fy)
              : make_float4(0.f, 0.f, 0.f, 0.f);
    ad = valid ? a : 0;
}

__device__ __forceinline__ float tap4(const float* __restrict__ im, int ad, float4 w) {
    const float* t = im + ad;
    return fmaf(w.x, t[0], fmaf(w.y, t[1], fmaf(w.z, t[128], w.w * t[129])));
}

// Kernel 2: one block per (b, 16-channel group), 1024 threads, dbuf LDS.
// 2-DEEP register pipeline, loads issued in (sat, image) pairs:
//   prologue: issue sv[0],img[0],sv[1],img[1]
//   iter k:   ds_write(img[k])          <- compiler waits vmcnt(2): (k+1)
//             issue sv[k+2],img[k+2]       pair stays IN FLIGHT
//             lgkm-only barrier
//             compute with sv[k] (already retired by the ds_write wait)
// -> no mid-compute vmcnt stall; every load has ~2 iterations of hiding.
// r12 lesson: sv issued after img and consumed mid-compute drained the
// prefetch every iteration (vmcnt is ordered).
template <bool PRECOMP>
__global__ __launch_bounds__(TPB) void proj_kernel(
        const float* __restrict__ grd,
        const float4* __restrict__ uv,
        const float* __restrict__ sat,
        float* __restrict__ out,
        const float* __restrict__ ph,    // inline-fallback path
        const float* __restrict__ shift_u,
        const float* __restrict__ shift_v,
        const float* __restrict__ heading,
        const float* __restrict__ camk) {
    __shared__ float img[2 * HW + 132];
    int cg = blockIdx.x, b = blockIdx.y;
    int c0 = cg * CPB;
    int tid = threadIdx.x;
    int p0 = tid * 4;
    int bbase = b << 12;

    const float* gbase = grd + ((size_t)b * C_ + c0) * HW;
    const float* satbase = sat + (size_t)c0 * AA + p0;
    float* outbase = out + ((size_t)b * C_ + c0) * AA + p0;

    // prologue: 2-deep issue, sv before img in each pair
    float4 svA = *(const float4*)(satbase);                    // sv[0]
    float4 imA = ((const float4*)gbase)[tid];                  // img[0]
    float4 svB = *(const float4*)(satbase + (size_t)AA);       // sv[1]
    float4 imB = ((const float4*)(gbase + HW))[tid];           // img[1]

    // zero-init buf1 head + permanent tail (overflow-tap safety on iter 0)
    if (tid < 33) {
        ((float4*)(img + HW))[tid] = make_float4(0.f, 0.f, 0.f, 0.f);
        ((float4*)(img + 2 * HW))[tid] = make_float4(0.f, 0.f, 0.f, 0.f);
    }

    // per-position sampling descriptors, computed once for all 16 channels
    float4 w[4][2];
    int ad[4][2];
    if (PRECOMP) {
        const float4* uvb = uv + bbase;
#pragma unroll
        for (int k = 0; k < 4; ++k) {
            float4 q = uvb[p0 + k];
            mk(q.x, q.y, w[k][0], ad[k][0]);
            mk(q.z, q.w, w[k][1], ad[k][1]);
        }
    } else {
        Pmat P = make_P(b, shift_u, shift_v, heading, camk);
        const float* phb = ph + bbase;
#pragma unroll
        for (int k = 0; k < 4; ++k) {
            float4 q = uv_at(P, p0 + k, -phb[p0 + k]);
            mk(q.x, q.y, w[k][0], ad[k][0]);
            mk(q.z, q.w, w[k][1], ad[k][1]);
        }
    }

#pragma unroll
    for (int k = 0; k < CPB; ++k) {
        const int bufo = (k & 1) * HW;
        // stage current channel (regs -> LDS); compiler's vmcnt here leaves
        // the (k+1) pair in flight (it was issued after img[k]).
        float4 imCur = (k & 1) ? imB : imA;
        float4 svCur = (k & 1) ? svB : svA;
        *(float4*)(img + bufo + p0) = imCur;

        // issue the (k+2) pair into the freed regs (sv first, then img)
        if (k + 2 < CPB) {
            float4 nsv = *(const float4*)(satbase + (size_t)(k + 2) * AA);
            float4 nim = ((const float4*)(gbase + (size_t)(k + 2) * HW))[tid];
            if (k & 1) { svB = nsv; imB = nim; }
            else       { svA = nsv; imA = nim; }
        }

        // barrier with LDS-only drain: vmem prefetches stay in flight
        asm volatile("s_waitcnt lgkmcnt(0)" ::: "memory");
        __builtin_amdgcn_s_barrier();

        const float* im = img + bufo;
        float r[4];
#pragma unroll
        for (int kk = 0; kk < 4; ++kk) {
            float g0 = tap4(im, ad[kk][0], w[kk][0]);
            float gh = tap4(im, ad[kk][1], w[kk][1]);
            float s = (kk == 0) ? svCur.x : (kk == 1) ? svCur.y
                    : (kk == 2) ? svCur.z : svCur.w;
            r[kk] = fmaf(s, gh - g0, g0);
        }
        vf4 rv = {r[0], r[1], r[2], r[3]};
        __builtin_nontemporal_store(rv, (vf4*)(outbase + (size_t)k * AA));
        // Laggard-safety: reads of buffer X (iter k) are drained by each
        // wave's own lgkmcnt(0) before barrier k+1; writers of X (iter k+2)
        // only write after barrier k+1 -> no read/write race.
    }
}

extern "C" void kernel_launch(void* const* d_in, const int* in_sizes, int n_in,
                              void* d_out, int out_size, void* d_ws, size_t ws_size,
                              hipStream_t stream) {
    (void)in_sizes; (void)n_in; (void)out_size;
    const float* grd  = (const float*)d_in[0];   // [B,C,H,W]
    const float* ph   = (const float*)d_in[1];   // [B,1,A,A]
    const float* s_u  = (const float*)d_in[2];   // [B,1]
    const float* s_v  = (const float*)d_in[3];   // [B,1]
    const float* hd   = (const float*)d_in[4];   // [B,1]
    const float* ck   = (const float*)d_in[5];   // [B,3,3]
    const float* sat  = (const float*)d_in[6];   // [1,C,A,A]
    float* out = (float*)d_out;

    const size_t uv_bytes = (size_t)NPOS * sizeof(float4);   // 2 MiB
    if (ws_size >= uv_bytes) {
        float4* uvws = (float4*)d_ws;
        uv_kernel<<<(NPOS + 255) / 256, 256, 0, stream>>>(ph, s_u, s_v, hd, ck, uvws);
        proj_kernel<true><<<dim3(C_ / CPB, B_), TPB, 0, stream>>>(
            grd, uvws, sat, out, ph, s_u, s_v, hd, ck);
    } else {
        proj_kernel<false><<<dim3(C_ / CPB, B_), TPB, 0, stream>>>(
            grd, nullptr, sat, out, ph, s_u, s_v, hd, ck);
    }
}

// Round 14
// 47.353 us; speedup vs baseline: 1.4332x; 1.0919x over previous
//
#include <hip/hip_runtime.h>
#include <math.h>

namespace {
constexpr int B_ = 32, C_ = 256, H_ = 32, W_ = 128, A_ = 64;
constexpr int AA = A_ * A_;       // 4096 positions per batch
constexpr int HW = H_ * W_;       // 4096 floats per (b,c) image = 16 KB
constexpr int CPB = 16;           // channels per block -> 512 blocks = 2/CU fill
constexpr int TPB = 1024;         // threads per block (16 waves)
constexpr float MPP = 1.6f;       // 0.2 * 512 / 64
constexpr float PI_F = 3.14159265358979323846f;
typedef float vf4 __attribute__((ext_vector_type(4)));   // native vec for NT store
}

struct Pmat {
    float p00, p01, p02, p03;
    float p10, p11, p12, p13;
    float p20, p21, p22, p23;
};

__device__ __forceinline__ Pmat make_P(int b,
                                       const float* __restrict__ shift_u,
                                       const float* __restrict__ shift_v,
                                       const float* __restrict__ heading,
                                       const float* __restrict__ camk) {
    float su = 20.f * shift_u[b];
    float sv = 20.f * shift_v[b];
    float h  = heading[b] * (10.f / 180.f) * PI_F;
    float ch = cosf(h);
    float sh = -sinf(h);   // sin(-h)

    const float* K = camk + b * 9;
    float k00 = K[0] * 0.125f, k01 = K[1] * 0.125f, k02 = K[2] * 0.125f;
    float k10 = K[3] * 0.125f, k11 = K[4] * 0.125f, k12 = K[5] * 0.125f;
    float k20 = K[6],          k21 = K[7],          k22 = K[8];

    Pmat P;
    P.p00 = k00 * ch + k02 * sh;  P.p01 = k01;
    P.p02 = -k00 * sh + k02 * ch; P.p03 = k00 * sv + k01 * 1.65f - k02 * su;
    P.p10 = k10 * ch + k12 * sh;  P.p11 = k11;
    P.p12 = -k10 * sh + k12 * ch; P.p13 = k10 * sv + k11 * 1.65f - k12 * su;
    P.p20 = k20 * ch + k22 * sh;  P.p21 = k21;
    P.p22 = -k20 * sh + k22 * ch; P.p23 = k20 * sv + k21 * 1.65f - k22 * su;
    return P;
}

__device__ __forceinline__ float4 uv_at(const Pmat& P, int pos, float Y) {
    int i = pos >> 6, j = pos & 63;
    float X = MPP * (float)(i - 32);
    float Z = MPP * (float)(j - 32);

    float u1 = P.p00 * X + P.p02 * Z + P.p03;
    float v1 = P.p10 * X + P.p12 * Z + P.p13;
    float w1 = P.p20 * X + P.p22 * Z + P.p23;

    float d0 = fmaxf(w1, 1e-6f);
    float u0 = u1 / d0, v0 = v1 / d0;

    float u1h = u1 + P.p01 * Y;
    float v1h = v1 + P.p11 * Y;
    float w1h = w1 + P.p21 * Y;
    float dh = fmaxf(w1h, 1e-6f);
    float uh = u1h / dh, vh = v1h / dh;

    return make_float4(u0, v0, uh, vh);
}

// Weights premultiplied by valid; LDS dword index, unclamped +1/+128/+129 taps.
// Edge overflow taps carry weight exactly 0; they read the other buffer /
// zero tail, which is guaranteed finite (never NaN/inf from uninit).
__device__ __forceinline__ void mk(float ix, float iy, float4& w, int& ad) {
    bool valid = (ix >= 0.f) && (ix <= (float)(W_ - 1)) &&
                 (iy >= 0.f) && (iy <= (float)(H_ - 1));
    float x0f = floorf(ix), y0f = floorf(iy);
    float fx = ix - x0f, fy = iy - y0f;
    float xa = fminf(fmaxf(x0f, 0.f), 127.f);
    float ya = fminf(fmaxf(y0f, 0.f), 31.f);
    int a = (int)fmaf(ya, 128.f, xa);
    float gx = 1.f - fx, gy = 1.f - fy;
    w = valid ? make_float4(gx * gy, fx * gy, gx * fy, fx * fy)
              : make_float4(0.f, 0.f, 0.f, 0.f);
    ad = valid ? a : 0;
}

__device__ __forceinline__ float tap4(const float* __restrict__ im, int ad, float4 w) {
    const float* t = im + ad;
    return fmaf(w.x, t[0], fmaf(w.y, t[1], fmaf(w.z, t[128], w.w * t[129])));
}

// SINGLE fused kernel (r11 structure + inline descriptors): one block per
// (b, 16-channel group) -> 512 blocks x 16 waves = 2 blocks/CU. Descriptors
// (make_P + uv_at + mk) computed ONCE per thread inline — no uv_kernel, no
// workspace. Per channel: {ds_write staged image -> reg-prefetch next ->
// lgkmcnt-only barrier (prefetch stays in flight) -> compute + NT store}.
__global__ __launch_bounds__(TPB) void proj_kernel(
        const float* __restrict__ grd,
        const float* __restrict__ sat,
        float* __restrict__ out,
        const float* __restrict__ ph,
        const float* __restrict__ shift_u,
        const float* __restrict__ shift_v,
        const float* __restrict__ heading,
        const float* __restrict__ camk) {
    __shared__ float img[2 * HW + 132];
    int cg = blockIdx.x, b = blockIdx.y;
    int c0 = cg * CPB;
    int tid = threadIdx.x;
    int p0 = tid * 4;
    int bbase = b << 12;

    const float* gbase = grd + ((size_t)b * C_ + c0) * HW;

    // prologue: issue load of channel 0 image (1 float4/thread)
    float4 streg = ((const float4*)gbase)[tid];

    // zero-init buf1 head + permanent tail (overflow-tap safety on iter 0)
    if (tid < 33) {
        ((float4*)(img + HW))[tid] = make_float4(0.f, 0.f, 0.f, 0.f);
        ((float4*)(img + 2 * HW))[tid] = make_float4(0.f, 0.f, 0.f, 0.f);
    }

    // per-position sampling descriptors, computed once for all 16 channels
    float4 w[4][2];
    int ad[4][2];
    {
        Pmat P = make_P(b, shift_u, shift_v, heading, camk);
        const float* phb = ph + bbase;
#pragma unroll
        for (int k = 0; k < 4; ++k) {
            float4 q = uv_at(P, p0 + k, -phb[p0 + k]);
            mk(q.x, q.y, w[k][0], ad[k][0]);
            mk(q.z, q.w, w[k][1], ad[k][1]);
        }
    }

    float* outbase = out + ((size_t)b * C_ + c0) * AA + p0;
    const float* satbase = sat + (size_t)c0 * AA + p0;

#pragma unroll
    for (int cp = 0; cp < CPB; ++cp) {
        int bufo = (cp & 1) * HW;
        // stage current channel (regs -> LDS)
        *(float4*)(img + bufo + p0) = streg;
        // prefetch next channel (stays in flight across the barrier)
        float4 nxt;
        if (cp + 1 < CPB)
            nxt = ((const float4*)(gbase + (size_t)(cp + 1) * HW))[tid];
        float4 sv = *(const float4*)(satbase + (size_t)cp * AA);
        // barrier with LDS-only drain: do NOT wait vmcnt (prefetch in flight)
        asm volatile("s_waitcnt lgkmcnt(0)" ::: "memory");
        __builtin_amdgcn_s_barrier();

        const float* im = img + bufo;
        float r[4];
#pragma unroll
        for (int k = 0; k < 4; ++k) {
            float g0 = tap4(im, ad[k][0], w[k][0]);
            float gh = tap4(im, ad[k][1], w[k][1]);
            float s = (k == 0) ? sv.x : (k == 1) ? sv.y : (k == 2) ? sv.z : sv.w;
            r[k] = fmaf(s, gh - g0, g0);
        }
        vf4 rv = {r[0], r[1], r[2], r[3]};
        __builtin_nontemporal_store(rv, (vf4*)(outbase + (size_t)cp * AA));
        streg = nxt;
        // Laggard-safety: a wave's reads of buffer X (iter cp) are drained by
        // its own lgkmcnt(0) before barrier cp+1; writers of X (iter cp+2)
        // write only after barrier cp+1 -> no read/write race.
    }
}

extern "C" void kernel_launch(void* const* d_in, const int* in_sizes, int n_in,
                              void* d_out, int out_size, void* d_ws, size_t ws_size,
                              hipStream_t stream) {
    (void)in_sizes; (void)n_in; (void)out_size; (void)d_ws; (void)ws_size;
    const float* grd  = (const float*)d_in[0];   // [B,C,H,W]
    const float* ph   = (const float*)d_in[1];   // [B,1,A,A]
    const float* s_u  = (const float*)d_in[2];   // [B,1]
    const float* s_v  = (const float*)d_in[3];   // [B,1]
    const float* hd   = (const float*)d_in[4];   // [B,1]
    const float* ck   = (const float*)d_in[5];   // [B,3,3]
    const float* sat  = (const float*)d_in[6];   // [1,C,A,A]
    float* out = (float*)d_out;

    proj_kernel<<<dim3(C_ / CPB, B_), TPB, 0, stream>>>(
        grd, sat, out, ph, s_u, s_v, hd, ck);
}